// Round 5
// baseline (182.592 us; speedup 1.0000x reference)
//
#include <hip/hip_runtime.h>
#include <stdint.h>

#define NT 4
#define PP 100
#define TT_BYTES (4ull * 100 * 100 * 1024)   // 40,960,000 B for tT in d_ws

// tT layout per combo (tab,i0,i1), 1 KB, AB-MAJOR (MFMA A-fragment friendly):
//   bf16 t[ab][s] at byte ab*64 + s*2   (ab 0..15, s 0..31)
//   lane l reads its A-frag (16 B) at (l&15)*64 + (l>>4)*16
// c2a layout (after tT in d_ws), B-fragment friendly, 100 KB:
//   dword index ((tab*100+i2)*4 + n)*16 + sgrp*4 + jp packs
//   lo = bf16 c2[s=sgrp*8+2jp][n], hi = bf16 c2[s+1][n]   (n 0..3)
//   lane l (n=l&15<4) reads its B-frag (16 B) at ((tab*100+i2)*4+n)*64 + (l>>4)*16

typedef __attribute__((ext_vector_type(8))) short short8;
typedef __attribute__((ext_vector_type(4))) float floatx4;
union U4S8 { uint4 u; short8 s; };

__device__ __forceinline__ uint32_t f2bf(float f) {
    union { float f; uint32_t u; } v; v.f = f;
    uint32_t u = v.u;
    return (u + 0x7fffu + ((u >> 16) & 1u)) >> 16;   // RNE to bf16
}

// ---------------- Phase 0: pack c2 into B-fragment layout ----------------
__global__ __launch_bounds__(256)
void c2pack_kernel(const float* __restrict__ c2g, uint32_t* __restrict__ c2a) {
    int t = blockIdx.x * 256 + threadIdx.x;       // dword id
    if (t >= NT * PP * 64) return;
    int jp = t & 3, sgrp = (t >> 2) & 3, n = (t >> 4) & 3, rest = t >> 6;
    int i2 = rest % PP, tab = rest / PP;
    const float* src = c2g + (size_t)(tab * PP + i2) * 128;
    int s = sgrp * 8 + 2 * jp;
    c2a[t] = f2bf(src[s * 4 + n]) | (f2bf(src[(s + 1) * 4 + n]) << 16);
}

// ---------------- Phase 1: t[tab,i0,i1] = c0[tab,i0] @ c1[tab,i1] ----------------
// grid: 4 tab * 100 i1 * 7 chunks(16 i0) = 2800 blocks, 128 threads.
// thread (u 0..7, sg 0..15): 2 i0 (2u,2u+1), s-pair (2sg,2sg+1), all 16 ab.
__global__ __launch_bounds__(128, 3)
void tt_phase1(const float* __restrict__ c0g, const float* __restrict__ c1g,
               unsigned short* __restrict__ tT) {
    __shared__ float c1s[32 * 128];   // [r][b*32+s]
    __shared__ float c0t[16 * 132];   // [i0l][r*4+a] (padded stride)

    int blk = blockIdx.x;
    int tab   = blk / 700;
    int rem   = blk % 700;
    int i1    = rem / 7;
    int chunk = rem % 7;
    int i0_base = chunk * 16;
    int tid = threadIdx.x;

    const float4* c1p = (const float4*)(c1g + (size_t)(tab * PP + i1) * 4096);
    float4* c1v = (float4*)c1s;
    #pragma unroll
    for (int it = 0; it < 8; ++it) c1v[tid + 128 * it] = c1p[tid + 128 * it];

    #pragma unroll
    for (int it = 0; it < 16; ++it) {
        int f = tid + 128 * it;          // 0..2047
        int i0l = f >> 7;
        int x   = f & 127;               // a*32 + r
        int a = x >> 5, r = x & 31;
        int i0 = i0_base + i0l; if (i0 > PP - 1) i0 = PP - 1;
        c0t[i0l * 132 + r * 4 + a] = c0g[(size_t)(tab * PP + i0) * 128 + x];
    }
    __syncthreads();

    int u  = tid >> 4;                   // 0..7
    int sg = tid & 15;

    float acc[2][2][16];                 // [i0 sel][e (s parity)][ab]
    #pragma unroll
    for (int ii = 0; ii < 2; ++ii)
        #pragma unroll
        for (int e = 0; e < 2; ++e)
            #pragma unroll
            for (int q = 0; q < 16; ++q) acc[ii][e][q] = 0.f;

    #pragma unroll 4
    for (int r = 0; r < 32; ++r) {
        float4 av0 = *(const float4*)&c0t[(2 * u) * 132 + r * 4];
        float4 av1 = *(const float4*)&c0t[(2 * u + 1) * 132 + r * 4];
        const float* a0 = (const float*)&av0;
        const float* a1 = (const float*)&av1;
        #pragma unroll
        for (int b = 0; b < 4; ++b) {
            float2 bv = *(const float2*)&c1s[r * 128 + b * 32 + 2 * sg];
            #pragma unroll
            for (int a = 0; a < 4; ++a) {
                acc[0][0][a * 4 + b] += a0[a] * bv.x;
                acc[0][1][a * 4 + b] += a0[a] * bv.y;
                acc[1][0][a * 4 + b] += a1[a] * bv.x;
                acc[1][1][a * 4 + b] += a1[a] * bv.y;
            }
        }
    }

    // store ab-major: dword (t[ab][2sg], t[ab][2sg+1]) at dword index ab*16 + sg.
    // per store instr: 16 sg lanes x 4 B contiguous (64 B runs) x 4 u-combos.
    #pragma unroll
    for (int ii = 0; ii < 2; ++ii) {
        int i0 = i0_base + 2 * u + ii;
        if (i0 >= PP) continue;
        size_t combo = (size_t)tab * 10000 + (size_t)i0 * 100 + (size_t)i1;
        uint32_t* bp = (uint32_t*)((char*)tT + combo * 1024) + sg;
        #pragma unroll
        for (int ab = 0; ab < 16; ++ab)
            bp[ab * 16] = f2bf(acc[ii][0][ab]) | (f2bf(acc[ii][1][ab]) << 16);
    }
}

// ---------------- Phase 2: MFMA gather-contract-pool ----------------
// 1 wave per bag, 4 waves/block. Per lookup: one v_mfma_f32_16x16x32_bf16
// (A = t[16ab x 32s], B = c2[32s x 4c] zero-padded to 16 cols). Pooling is
// free (16 lookups accumulate into one C frag). All 16 A-frag loads hoisted.
__global__ __launch_bounds__(256, 4)
void tt_phase2(const int* __restrict__ indices, const int* __restrict__ offsets,
               const unsigned short* __restrict__ tT, const uint32_t* __restrict__ c2a,
               float* __restrict__ out, int bags_per_table, int B) {
    int lane = threadIdx.x & 63;
    int wv   = threadIdx.x >> 6;
    int blk  = blockIdx.x;

    // XCD-affine bag mapping (perf heuristic): xcd = blk&7 serves table xcd>>1,
    // shrinking each XCD's tT working set 41 MB -> 10 MB.
    int tab, bag;
    if (((gridDim.x & 7) == 0) && ((B & 31) == 0)) {
        int xcd = blk & 7;
        tab = xcd >> 1;
        int within = ((blk >> 3) << 1) + (xcd & 1);
        bag = tab * bags_per_table + within * 4 + wv;
    } else {
        bag = blk * 4 + wv;
        tab = bag / bags_per_table;
    }
    if (bag >= B) return;

    int n = lane & 15, quad = lane >> 4;
    int laneoff = n * 64 + quad * 16;     // byte offset within a 1 KB frag slab

    int start = offsets[bag];
    // every lane computes the packed code for lookup (lane&15)
    uint32_t idx = (uint32_t)indices[start + n];
    uint32_t i0 = idx / 10000u;
    uint32_t r1 = idx - i0 * 10000u;
    uint32_t i1 = r1 / 100u;
    uint32_t i2 = r1 - i1 * 100u;
    uint32_t code = (i0 * 100u + i1) * 128u + i2;   // combo<<7 | i2

    const char* tbase = (const char*)tT + (size_t)tab * 10000u * 1024u + laneoff;
    const char* cbase = (const char*)c2a + (size_t)tab * PP * 256u + laneoff;
    bool bact = (n < 4);

    uint32_t codes[16];
    uint4 af[16];
    #pragma unroll
    for (int j = 0; j < 16; ++j) {
        uint32_t cj = __shfl((int)code, j, 64);
        codes[j] = cj;
        af[j] = *(const uint4*)(tbase + (size_t)(cj >> 7) * 1024u);
    }

    floatx4 acc = {0.f, 0.f, 0.f, 0.f};
    uint4 zero4 = make_uint4(0u, 0u, 0u, 0u);
    #pragma unroll
    for (int j = 0; j < 16; ++j) {
        uint4 bu = bact ? *(const uint4*)(cbase + (size_t)(codes[j] & 127u) * 256u) : zero4;
        U4S8 a, b; a.u = af[j]; b.u = bu;
        acc = __builtin_amdgcn_mfma_f32_16x16x32_bf16(a.s, b.s, acc, 0, 0, 0);
    }

    // C/D layout: col = lane&15 (= c), row = quad*4 + reg (= ab).
    // out[bag][ab*4 + c] = out[bag][quad*16 + reg*4 + n], only n<4 lanes live.
    if (bact) {
        float* op = out + (size_t)bag * 64 + quad * 16 + n;
        op[0]  = acc[0];
        op[4]  = acc[1];
        op[8]  = acc[2];
        op[12] = acc[3];
    }
}

extern "C" void kernel_launch(void* const* d_in, const int* in_sizes, int n_in,
                              void* d_out, int out_size, void* d_ws, size_t ws_size,
                              hipStream_t stream) {
    const int*   indices = (const int*)d_in[0];
    const int*   offsets = (const int*)d_in[1];
    const float* c0      = (const float*)d_in[2];
    const float* c1      = (const float*)d_in[3];
    const float* c2      = (const float*)d_in[4];
    float* out = (float*)d_out;

    int B = in_sizes[1] - 1;              // 32768 bags
    int bags_per_table = B / NT;          // 8192

    unsigned short* tT  = (unsigned short*)d_ws;
    uint32_t*       c2a = (uint32_t*)((char*)d_ws + TT_BYTES);   // +100 KB

    c2pack_kernel<<<dim3((NT * PP * 64 + 255) / 256), dim3(256), 0, stream>>>(c2, c2a);
    tt_phase1<<<dim3(NT * PP * 7), dim3(128), 0, stream>>>(c0, c1, tT);
    tt_phase2<<<dim3((B + 3) / 4), dim3(256), 0, stream>>>(indices, offsets, tT, c2a, out,
                                                           bags_per_table, B);
}

// Round 6
// 160.214 us; speedup vs baseline: 1.1397x; 1.1397x over previous
//
#include <hip/hip_runtime.h>
#include <stdint.h>

#define NT 4
#define PP 100
#define TT_BYTES (4ull * 100 * 100 * 1024)   // 40,960,000 B for tT in d_ws

// tT layout per combo (tab,i0,i1), 1 KB, AB-MAJOR (MFMA A-fragment friendly):
//   bf16 t[ab][s] at byte ab*64 + s*2   (ab 0..15, s 0..31)
//   lane l reads its A-frag (16 B) at (l&15)*64 + (l>>4)*16
// c2a layout (after tT in d_ws), B-fragment friendly, 100 KB:
//   dword index ((tab*100+i2)*4 + n)*16 + sgrp*4 + jp packs
//   lo = bf16 c2[s=sgrp*8+2jp][n], hi = bf16 c2[s+1][n]   (n 0..3)
//   lane l reads its B-frag (16 B) at ((tab*100+i2)*4+(l&3))*64 + (l>>4)*16
//   (columns 4..15 read duplicate data -> garbage only in discarded C cols)

typedef __attribute__((ext_vector_type(8))) short short8;
typedef __attribute__((ext_vector_type(4))) float floatx4;
union U4S8 { uint4 u; short8 s; };

__device__ __forceinline__ uint32_t f2bf(float f) {
    union { float f; uint32_t u; } v; v.f = f;
    uint32_t u = v.u;
    return (u + 0x7fffu + ((u >> 16) & 1u)) >> 16;   // RNE to bf16
}

// ---------------- Phase 0: pack c2 into B-fragment layout ----------------
__global__ __launch_bounds__(256)
void c2pack_kernel(const float* __restrict__ c2g, uint32_t* __restrict__ c2a) {
    int t = blockIdx.x * 256 + threadIdx.x;       // dword id
    if (t >= NT * PP * 64) return;
    int jp = t & 3, sgrp = (t >> 2) & 3, n = (t >> 4) & 3, rest = t >> 6;
    int i2 = rest % PP, tab = rest / PP;
    const float* src = c2g + (size_t)(tab * PP + i2) * 128;
    int s = sgrp * 8 + 2 * jp;
    c2a[t] = f2bf(src[s * 4 + n]) | (f2bf(src[(s + 1) * 4 + n]) << 16);
}

// ---------------- Phase 1: t[tab,i0,i1] = c0[tab,i0] @ c1[tab,i1] ----------------
// grid: 4 tab * 100 i1 * 7 chunks(16 i0) = 2800 blocks, 128 threads.
// thread (u 0..7, sg 0..15): 2 i0 (2u,2u+1), s-pair (2sg,2sg+1), all 16 ab.
__global__ __launch_bounds__(128, 3)
void tt_phase1(const float* __restrict__ c0g, const float* __restrict__ c1g,
               unsigned short* __restrict__ tT) {
    __shared__ float c1s[32 * 128];   // [r][b*32+s]
    __shared__ float c0t[16 * 132];   // [i0l][r*4+a] (padded stride)

    int blk = blockIdx.x;
    int tab   = blk / 700;
    int rem   = blk % 700;
    int i1    = rem / 7;
    int chunk = rem % 7;
    int i0_base = chunk * 16;
    int tid = threadIdx.x;

    const float4* c1p = (const float4*)(c1g + (size_t)(tab * PP + i1) * 4096);
    float4* c1v = (float4*)c1s;
    #pragma unroll
    for (int it = 0; it < 8; ++it) c1v[tid + 128 * it] = c1p[tid + 128 * it];

    #pragma unroll
    for (int it = 0; it < 16; ++it) {
        int f = tid + 128 * it;          // 0..2047
        int i0l = f >> 7;
        int x   = f & 127;               // a*32 + r
        int a = x >> 5, r = x & 31;
        int i0 = i0_base + i0l; if (i0 > PP - 1) i0 = PP - 1;
        c0t[i0l * 132 + r * 4 + a] = c0g[(size_t)(tab * PP + i0) * 128 + x];
    }
    __syncthreads();

    int u  = tid >> 4;                   // 0..7
    int sg = tid & 15;

    float acc[2][2][16];                 // [i0 sel][e (s parity)][ab]
    #pragma unroll
    for (int ii = 0; ii < 2; ++ii)
        #pragma unroll
        for (int e = 0; e < 2; ++e)
            #pragma unroll
            for (int q = 0; q < 16; ++q) acc[ii][e][q] = 0.f;

    #pragma unroll 4
    for (int r = 0; r < 32; ++r) {
        float4 av0 = *(const float4*)&c0t[(2 * u) * 132 + r * 4];
        float4 av1 = *(const float4*)&c0t[(2 * u + 1) * 132 + r * 4];
        const float* a0 = (const float*)&av0;
        const float* a1 = (const float*)&av1;
        #pragma unroll
        for (int b = 0; b < 4; ++b) {
            float2 bv = *(const float2*)&c1s[r * 128 + b * 32 + 2 * sg];
            #pragma unroll
            for (int a = 0; a < 4; ++a) {
                acc[0][0][a * 4 + b] += a0[a] * bv.x;
                acc[0][1][a * 4 + b] += a0[a] * bv.y;
                acc[1][0][a * 4 + b] += a1[a] * bv.x;
                acc[1][1][a * 4 + b] += a1[a] * bv.y;
            }
        }
    }

    // store ab-major: dword (t[ab][2sg], t[ab][2sg+1]) at dword index ab*16 + sg.
    #pragma unroll
    for (int ii = 0; ii < 2; ++ii) {
        int i0 = i0_base + 2 * u + ii;
        if (i0 >= PP) continue;
        size_t combo = (size_t)tab * 10000 + (size_t)i0 * 100 + (size_t)i1;
        uint32_t* bp = (uint32_t*)((char*)tT + combo * 1024) + sg;
        #pragma unroll
        for (int ab = 0; ab < 16; ++ab)
            bp[ab * 16] = f2bf(acc[ii][0][ab]) | (f2bf(acc[ii][1][ab]) << 16);
    }
}

// ---------------- Phase 2: MFMA gather-contract-pool ----------------
// 1 wave per bag, 4 waves/block. Per lookup: one v_mfma_f32_16x16x32_bf16
// (A = t[16ab x 32s], B = c2[32s x 4c], cols 4..15 garbage-discarded).
// ALL 32 loads (16 A-frag + 16 B-frag) hoisted before the MFMA loop; two
// interleaved accumulators; epilogue via LDS -> 256 B contiguous store/bag.
__global__ __launch_bounds__(256, 3)
void tt_phase2(const int* __restrict__ indices, const int* __restrict__ offsets,
               const unsigned short* __restrict__ tT, const uint32_t* __restrict__ c2a,
               float* __restrict__ out, int bags_per_table, int B) {
    __shared__ float obuf[4][64];
    int lane = threadIdx.x & 63;
    int wv   = threadIdx.x >> 6;
    int blk  = blockIdx.x;

    // XCD-affine bag mapping: xcd = blk&7 serves table xcd>>1 (tT set 10 MB/XCD).
    int tab, bag;
    if (((gridDim.x & 7) == 0) && ((B & 31) == 0)) {
        int xcd = blk & 7;
        tab = xcd >> 1;
        int within = ((blk >> 3) << 1) + (xcd & 1);
        bag = tab * bags_per_table + within * 4 + wv;
    } else {
        bag = blk * 4 + wv;
        tab = bag / bags_per_table;
    }
    if (bag >= B) return;

    int n = lane & 15, quad = lane >> 4;
    int aoff = n * 64 + quad * 16;           // A-frag byte offset in 1 KB slab
    int boff = (n & 3) * 64 + quad * 16;     // B-frag byte offset in 256 B slab

    int start = offsets[bag];
    uint32_t idx = (uint32_t)indices[start + n];   // lane's lookup (n = slot)
    uint32_t i0 = idx / 10000u;
    uint32_t r1 = idx - i0 * 10000u;
    uint32_t i1 = r1 / 100u;
    uint32_t i2 = r1 - i1 * 100u;
    uint32_t code = (i0 * 100u + i1) * 128u + i2;  // combo<<7 | i2

    const char* tbase = (const char*)tT + (size_t)tab * 10000u * 1024u + aoff;
    const char* cbase = (const char*)c2a + (size_t)tab * PP * 256u + boff;

    uint32_t codes[16];
    #pragma unroll
    for (int j = 0; j < 16; ++j) codes[j] = __shfl((int)code, j, 64);

    uint4 af[16], bf[16];
    #pragma unroll
    for (int j = 0; j < 16; ++j)
        af[j] = *(const uint4*)(tbase + (size_t)(codes[j] >> 7) * 1024u);
    #pragma unroll
    for (int j = 0; j < 16; ++j)
        bf[j] = *(const uint4*)(cbase + (size_t)(codes[j] & 127u) * 256u);

    floatx4 acc0 = {0.f, 0.f, 0.f, 0.f};
    floatx4 acc1 = {0.f, 0.f, 0.f, 0.f};
    #pragma unroll
    for (int j = 0; j < 16; j += 2) {
        U4S8 a0, b0, a1, b1;
        a0.u = af[j];     b0.u = bf[j];
        a1.u = af[j + 1]; b1.u = bf[j + 1];
        acc0 = __builtin_amdgcn_mfma_f32_16x16x32_bf16(a0.s, b0.s, acc0, 0, 0, 0);
        acc1 = __builtin_amdgcn_mfma_f32_16x16x32_bf16(a1.s, b1.s, acc1, 0, 0, 0);
    }

    // C/D layout: col = lane&15 (= c, live for c<4), row = quad*4 + reg (= ab).
    // out[bag][ab*4 + c] -> stage in LDS, then 16 lanes x float4 contiguous.
    if (n < 4) {
        #pragma unroll
        for (int r = 0; r < 4; ++r)
            obuf[wv][quad * 16 + r * 4 + n] = acc0[r] + acc1[r];
    }
    __asm__ volatile("s_waitcnt lgkmcnt(0)" ::: "memory");   // same-wave LDS handoff
    if (lane < 16) {
        float4 v = *(const float4*)&obuf[wv][lane * 4];
        ((float4*)(out + (size_t)bag * 64))[lane] = v;
    }
}

extern "C" void kernel_launch(void* const* d_in, const int* in_sizes, int n_in,
                              void* d_out, int out_size, void* d_ws, size_t ws_size,
                              hipStream_t stream) {
    const int*   indices = (const int*)d_in[0];
    const int*   offsets = (const int*)d_in[1];
    const float* c0      = (const float*)d_in[2];
    const float* c1      = (const float*)d_in[3];
    const float* c2      = (const float*)d_in[4];
    float* out = (float*)d_out;

    int B = in_sizes[1] - 1;              // 32768 bags
    int bags_per_table = B / NT;          // 8192

    unsigned short* tT  = (unsigned short*)d_ws;
    uint32_t*       c2a = (uint32_t*)((char*)d_ws + TT_BYTES);   // +100 KB

    c2pack_kernel<<<dim3((NT * PP * 64 + 255) / 256), dim3(256), 0, stream>>>(c2, c2a);
    tt_phase1<<<dim3(NT * PP * 7), dim3(128), 0, stream>>>(c0, c1, tT);
    tt_phase2<<<dim3((B + 3) / 4), dim3(256), 0, stream>>>(indices, offsets, tT, c2a, out,
                                                           bags_per_table, B);
}